// Round 1
// baseline (627.572 us; speedup 1.0000x reference)
//
#include <hip/hip_runtime.h>
#include <hip/hip_bf16.h>
#include <stdint.h>

#define DIN   1024
#define DOUT  1024
#define NHEAD 16
#define HDIM  64
#define SEQL  2048
#define BSZ   4
#define MTOT  (BSZ*SEQL)   // 8192
#define KDIM  1024

typedef __bf16 bf16x8 __attribute__((ext_vector_type(8)));
typedef float  f32x4  __attribute__((ext_vector_type(4)));

__device__ __forceinline__ f32x4 mfma16(bf16x8 a, bf16x8 b, f32x4 c) {
    return __builtin_amdgcn_mfma_f32_16x16x32_bf16(a, b, c, 0, 0, 0);
}

__device__ __forceinline__ void gl_lds16(const void* gsrc, void* ldst) {
    __builtin_amdgcn_global_load_lds(
        (const __attribute__((address_space(1))) uint32_t*)gsrc,
        (__attribute__((address_space(3))) uint32_t*)ldst, 16, 0, 0);
}

__device__ __forceinline__ unsigned short f2bf(float f) {
    union { __hip_bfloat16 h; unsigned short u; } cv;
    cv.h = __float2bfloat16(f);
    return cv.u;
}

// ---------------- fp32 -> bf16 elementwise (vectorized) ----------------
__global__ void cvt_bf16(const float4* __restrict__ in, ushort4* __restrict__ out, int n4) {
    int idx = blockIdx.x * blockDim.x + threadIdx.x;
    int stride = gridDim.x * blockDim.x;
    for (int i = idx; i < n4; i += stride) {
        float4 v = in[i];
        ushort4 o;
        o.x = f2bf(v.x); o.y = f2bf(v.y); o.z = f2bf(v.z); o.w = f2bf(v.w);
        out[i] = o;
    }
}

// ---------------- transpose + convert W[1024][1024] f32 -> Wt bf16 ----------------
__global__ void transpose_cvt(const float* __restrict__ W, __hip_bfloat16* __restrict__ Wt) {
    __shared__ __hip_bfloat16 t[32][33];
    const int tx = threadIdx.x, ty = threadIdx.y;   // (32, 8)
    const int bx = blockIdx.x, by = blockIdx.y;
#pragma unroll
    for (int r = 0; r < 4; ++r)
        t[ty + 8*r][tx] = __float2bfloat16(W[(size_t)(by*32 + ty + 8*r) * DOUT + bx*32 + tx]);
    __syncthreads();
#pragma unroll
    for (int r = 0; r < 4; ++r)
        Wt[(size_t)(bx*32 + ty + 8*r) * DIN + by*32 + tx] = t[tx][ty + 8*r];
}

// ---------------- 128x128-tile MFMA GEMM: C = A[M,K] * Bt[N,K]^T + bias ----------------
// EPI 0: bf16 out, head-major [B,H,S,64], (acc+bias)*scale
// EPI 1: bf16 out, transposed  [B,H,64,S]
// EPI 2: f32 out, row-major [M,N]
template <int EPI>
__global__ __launch_bounds__(256)
void gemm_mfma(const __hip_bfloat16* __restrict__ A,
               const __hip_bfloat16* __restrict__ Bt,
               const float* __restrict__ bias,
               void* __restrict__ out,
               float scale)
{
    __shared__ alignas(16) __hip_bfloat16 As[2][4][128][8];
    __shared__ alignas(16) __hip_bfloat16 Bs[2][4][128][8];

    const int tid  = threadIdx.x;
    const int w    = tid >> 6;
    const int lane = tid & 63;
    const int g    = lane >> 4;
    const int r    = lane & 15;
    const int wr   = w >> 1, wc = w & 1;

    const int row0 = blockIdx.y * 128;
    const int col0 = blockIdx.x * 128;

    f32x4 acc[4][4];
#pragma unroll
    for (int m = 0; m < 4; ++m)
#pragma unroll
        for (int n = 0; n < 4; ++n) acc[m][n] = (f32x4)0.0f;

    auto stage = [&](int buf, int kt) {
        const __hip_bfloat16* ga = A  + (size_t)(row0 + lane) * KDIM + kt*32 + 8*w;
        const __hip_bfloat16* gb = Bt + (size_t)(col0 + lane) * KDIM + kt*32 + 8*w;
        gl_lds16(ga,            &As[buf][w][0][0]);
        gl_lds16(ga + 64*KDIM,  &As[buf][w][64][0]);
        gl_lds16(gb,            &Bs[buf][w][0][0]);
        gl_lds16(gb + 64*KDIM,  &Bs[buf][w][64][0]);
    };

    stage(0, 0);
    __syncthreads();

    const int NKT = KDIM / 32;
    for (int kt = 0; kt < NKT; ++kt) {
        const int cur = kt & 1;
        if (kt + 1 < NKT) stage(cur ^ 1, kt + 1);

        bf16x8 af[4], bfr[4];
#pragma unroll
        for (int m = 0; m < 4; ++m)
            af[m] = *reinterpret_cast<const bf16x8*>(&As[cur][g][64*wr + 16*m + r][0]);
#pragma unroll
        for (int n = 0; n < 4; ++n)
            bfr[n] = *reinterpret_cast<const bf16x8*>(&Bs[cur][g][64*wc + 16*n + r][0]);

#pragma unroll
        for (int m = 0; m < 4; ++m)
#pragma unroll
            for (int n = 0; n < 4; ++n)
                acc[m][n] = mfma16(af[m], bfr[n], acc[m][n]);

        __syncthreads();
    }

#pragma unroll
    for (int n = 0; n < 4; ++n) {
        const int colg = col0 + 64*wc + 16*n + r;
        const float bv_ = bias[colg];
#pragma unroll
        for (int m = 0; m < 4; ++m) {
            const int rowg0 = row0 + 64*wr + 16*m + 4*g;
#pragma unroll
            for (int j = 0; j < 4; ++j) {
                const int rowg = rowg0 + j;
                const float v = (acc[m][n][j] + bv_) * scale;
                if (EPI == 0) {
                    const int b = rowg >> 11, s = rowg & (SEQL-1);
                    const int h = colg >> 6,  d = colg & (HDIM-1);
                    ((__hip_bfloat16*)out)[(((size_t)(b*NHEAD + h) * SEQL + s) << 6) + d] =
                        __float2bfloat16(v);
                } else if (EPI == 1) {
                    const int b = rowg >> 11, s = rowg & (SEQL-1);
                    const int h = colg >> 6,  d = colg & (HDIM-1);
                    ((__hip_bfloat16*)out)[((size_t)(b*NHEAD + h) * HDIM + d) * SEQL + s] =
                        __float2bfloat16(v);
                } else {
                    ((float*)out)[(size_t)rowg * DOUT + colg] = v;
                }
            }
        }
    }
}

// ---------------- causal flash attention ----------------
// Q,K: [B,H,S,64] bf16 (Q pre-scaled by 1/8).  Vt: [B,H,64,S] bf16.
// ctx out: [B,S,H*64] bf16 (row-major [8192][1024]).
__global__ __launch_bounds__(256)
void attn_fwd(const __hip_bfloat16* __restrict__ Q,
              const __hip_bfloat16* __restrict__ K,
              const __hip_bfloat16* __restrict__ Vt,
              __hip_bfloat16* __restrict__ ctx)
{
    __shared__ alignas(16) __hip_bfloat16 Ps[4][16][32];

    const int tid  = threadIdx.x;
    const int w    = tid >> 6;
    const int lane = tid & 63;
    const int g    = lane >> 4;
    const int r    = lane & 15;

    const int bh = blockIdx.y;
    const int b  = bh >> 4, h = bh & 15;
    const int qbase = blockIdx.x * 64 + w * 16;

    const __hip_bfloat16* Qh = Q  + (size_t)bh * SEQL * HDIM;
    const __hip_bfloat16* Kh = K  + (size_t)bh * SEQL * HDIM;
    const __hip_bfloat16* Vh = Vt + (size_t)bh * HDIM * SEQL;

    bf16x8 qf0 = *reinterpret_cast<const bf16x8*>(Qh + (size_t)(qbase + r)*HDIM + 8*g);
    bf16x8 qf1 = *reinterpret_cast<const bf16x8*>(Qh + (size_t)(qbase + r)*HDIM + 8*g + 32);

    f32x4 o[4];
#pragma unroll
    for (int n = 0; n < 4; ++n) o[n] = (f32x4)0.0f;
    float mrun[4], lrun[4];
#pragma unroll
    for (int j = 0; j < 4; ++j) { mrun[j] = -1e30f; lrun[j] = 0.0f; }

    const int nsteps = (qbase + 15) / 32 + 1;
    for (int kt = 0; kt < nsteps; ++kt) {
        const int key0 = kt * 32;

        f32x4 s[2];
#pragma unroll
        for (int c = 0; c < 2; ++c) {
            bf16x8 kf0 = *reinterpret_cast<const bf16x8*>(Kh + (size_t)(key0 + 16*c + r)*HDIM + 8*g);
            bf16x8 kf1 = *reinterpret_cast<const bf16x8*>(Kh + (size_t)(key0 + 16*c + r)*HDIM + 8*g + 32);
            f32x4 t = (f32x4)0.0f;
            t = mfma16(qf0, kf0, t);
            t = mfma16(qf1, kf1, t);
            s[c] = t;
        }

        if (kt == nsteps - 1) {   // causal mask only in the boundary step
#pragma unroll
            for (int c = 0; c < 2; ++c) {
                const int key = key0 + 16*c + r;
#pragma unroll
                for (int j = 0; j < 4; ++j)
                    if (key > qbase + 4*g + j) s[c][j] = -1e30f;
            }
        }

        // row max over 32 keys (2 tiles in regs + 16-lane shuffle groups)
        float tmax[4];
#pragma unroll
        for (int j = 0; j < 4; ++j) tmax[j] = fmaxf(s[0][j], s[1][j]);
#pragma unroll
        for (int off = 1; off < 16; off <<= 1)
#pragma unroll
            for (int j = 0; j < 4; ++j)
                tmax[j] = fmaxf(tmax[j], __shfl_xor(tmax[j], off, 16));

        float fac[4];
#pragma unroll
        for (int j = 0; j < 4; ++j) {
            const float mnew = fmaxf(mrun[j], tmax[j]);
            fac[j] = __expf(mrun[j] - mnew);
            mrun[j] = mnew;
        }
#pragma unroll
        for (int c = 0; c < 2; ++c)
#pragma unroll
            for (int j = 0; j < 4; ++j)
                s[c][j] = __expf(s[c][j] - mrun[j]);

        float psum[4];
#pragma unroll
        for (int j = 0; j < 4; ++j) psum[j] = s[0][j] + s[1][j];
#pragma unroll
        for (int off = 1; off < 16; off <<= 1)
#pragma unroll
            for (int j = 0; j < 4; ++j)
                psum[j] += __shfl_xor(psum[j], off, 16);
#pragma unroll
        for (int j = 0; j < 4; ++j) lrun[j] = lrun[j] * fac[j] + psum[j];
#pragma unroll
        for (int n = 0; n < 4; ++n)
#pragma unroll
            for (int j = 0; j < 4; ++j) o[n][j] *= fac[j];

        // P (C-layout) -> bf16 -> LDS -> A-fragment layout
#pragma unroll
        for (int c = 0; c < 2; ++c)
#pragma unroll
            for (int j = 0; j < 4; ++j)
                Ps[w][4*g + j][16*c + r] = __float2bfloat16(s[c][j]);
        bf16x8 pf = *reinterpret_cast<const bf16x8*>(&Ps[w][r][8*g]);

#pragma unroll
        for (int n = 0; n < 4; ++n) {
            bf16x8 vf = *reinterpret_cast<const bf16x8*>(Vh + (size_t)(16*n + r)*SEQL + key0 + 8*g);
            o[n] = mfma16(pf, vf, o[n]);
        }
    }

    float inv[4];
#pragma unroll
    for (int j = 0; j < 4; ++j) inv[j] = 1.0f / lrun[j];
#pragma unroll
    for (int n = 0; n < 4; ++n)
#pragma unroll
        for (int j = 0; j < 4; ++j) {
            const int srow = qbase + 4*g + j;
            const int col  = h*HDIM + 16*n + r;
            ctx[(size_t)(b*SEQL + srow) * DOUT + col] = __float2bfloat16(o[n][j] * inv[j]);
        }
}

extern "C" void kernel_launch(void* const* d_in, const int* in_sizes, int n_in,
                              void* d_out, int out_size, void* d_ws, size_t ws_size,
                              hipStream_t stream) {
    const float* x  = (const float*)d_in[0];
    const float* Wq = (const float*)d_in[1];
    const float* bq = (const float*)d_in[2];
    const float* Wk = (const float*)d_in[3];
    const float* bk = (const float*)d_in[4];
    const float* Wv = (const float*)d_in[5];
    const float* bv = (const float*)d_in[6];
    const float* Wo = (const float*)d_in[7];
    const float* bo = (const float*)d_in[8];
    float* out = (float*)d_out;
    (void)in_sizes; (void)n_in; (void)out_size; (void)ws_size;

    char* ws = (char*)d_ws;
    __hip_bfloat16* xb  = (__hip_bfloat16*)ws;                       // 16 MB
    __hip_bfloat16* Wqt = (__hip_bfloat16*)(ws + (16u << 20));       // 4 x 2 MB
    __hip_bfloat16* Wkt = Wqt + (size_t)DOUT * DIN;
    __hip_bfloat16* Wvt = Wkt + (size_t)DOUT * DIN;
    __hip_bfloat16* Wot = Wvt + (size_t)DOUT * DIN;
    __hip_bfloat16* Qb  = (__hip_bfloat16*)(ws + (24u << 20));       // 16 MB
    __hip_bfloat16* Kb  = Qb + (size_t)MTOT * DOUT;                  // 16 MB
    __hip_bfloat16* Vtb = Kb + (size_t)MTOT * DOUT;                  // 16 MB
    __hip_bfloat16* ctx = xb;  // alias: xb dead after the QKV GEMMs

    cvt_bf16<<<2048, 256, 0, stream>>>((const float4*)x, (ushort4*)xb, MTOT * DIN / 4);

    dim3 tb(32, 8), tg(32, 32);
    transpose_cvt<<<tg, tb, 0, stream>>>(Wq, Wqt);
    transpose_cvt<<<tg, tb, 0, stream>>>(Wk, Wkt);
    transpose_cvt<<<tg, tb, 0, stream>>>(Wv, Wvt);
    transpose_cvt<<<tg, tb, 0, stream>>>(Wo, Wot);

    dim3 gg(DOUT / 128, MTOT / 128);  // (8, 64)
    gemm_mfma<0><<<gg, 256, 0, stream>>>(xb, Wqt, bq, Qb, 0.125f);   // Q, scale folded
    gemm_mfma<0><<<gg, 256, 0, stream>>>(xb, Wkt, bk, Kb, 1.0f);     // K
    gemm_mfma<1><<<gg, 256, 0, stream>>>(xb, Wvt, bv, Vtb, 1.0f);    // V transposed

    dim3 ag(SEQL / 64, BSZ * NHEAD);  // (32, 64)
    attn_fwd<<<ag, 256, 0, stream>>>(Qb, Kb, Vtb, ctx);

    gemm_mfma<2><<<gg, 256, 0, stream>>>(ctx, Wot, bo, out, 1.0f);   // out proj, f32
}

// Round 2
// 332.787 us; speedup vs baseline: 1.8858x; 1.8858x over previous
//
#include <hip/hip_runtime.h>
#include <hip/hip_bf16.h>
#include <stdint.h>

#define DIN   1024
#define DOUT  1024
#define NHEAD 16
#define HDIM  64
#define SEQL  2048
#define BSZ   4
#define MTOT  (BSZ*SEQL)   // 8192
#define KDIM  1024

typedef __bf16 bf16x8 __attribute__((ext_vector_type(8)));
typedef float  f32x4  __attribute__((ext_vector_type(4)));

__device__ __forceinline__ f32x4 mfma16(bf16x8 a, bf16x8 b, f32x4 c) {
    return __builtin_amdgcn_mfma_f32_16x16x32_bf16(a, b, c, 0, 0, 0);
}

__device__ __forceinline__ void gl_lds16(const void* gsrc, void* ldst) {
    __builtin_amdgcn_global_load_lds(
        (const __attribute__((address_space(1))) uint32_t*)gsrc,
        (__attribute__((address_space(3))) uint32_t*)ldst, 16, 0, 0);
}

__device__ __forceinline__ unsigned short f2bf(float f) {
    union { __hip_bfloat16 h; unsigned short u; } cv;
    cv.h = __float2bfloat16(f);
    return cv.u;
}

// ---------------- fp32 -> bf16 elementwise (vectorized) ----------------
__global__ void cvt_bf16(const float4* __restrict__ in, ushort4* __restrict__ out, int n4) {
    int idx = blockIdx.x * blockDim.x + threadIdx.x;
    int stride = gridDim.x * blockDim.x;
    for (int i = idx; i < n4; i += stride) {
        float4 v = in[i];
        ushort4 o;
        o.x = f2bf(v.x); o.y = f2bf(v.y); o.z = f2bf(v.z); o.w = f2bf(v.w);
        out[i] = o;
    }
}

// ---------------- transpose + convert W[1024][1024] f32 -> Wt bf16 ----------------
__global__ void transpose_cvt(const float* __restrict__ W, __hip_bfloat16* __restrict__ Wt) {
    __shared__ __hip_bfloat16 t[32][33];
    const int tx = threadIdx.x, ty = threadIdx.y;   // (32, 8)
    const int bx = blockIdx.x, by = blockIdx.y;
#pragma unroll
    for (int r = 0; r < 4; ++r)
        t[ty + 8*r][tx] = __float2bfloat16(W[(size_t)(by*32 + ty + 8*r) * DOUT + bx*32 + tx]);
    __syncthreads();
#pragma unroll
    for (int r = 0; r < 4; ++r)
        Wt[(size_t)(bx*32 + ty + 8*r) * DIN + by*32 + tx] = t[tx][ty + 8*r];
}

// ---------------- 128x128-tile MFMA GEMM: C = A[M,K] * Bt[N,K]^T + bias ----------------
// EPI 0: bf16 out, head-major [B,H,S,64], (acc+bias)*scale
// EPI 1: bf16 out, transposed  [B,H,64,S]
// EPI 2: f32 out, row-major [M,N]
template <int EPI>
__global__ __launch_bounds__(256)
void gemm_mfma(const __hip_bfloat16* __restrict__ A,
               const __hip_bfloat16* __restrict__ Bt,
               const float* __restrict__ bias,
               void* __restrict__ out,
               float scale)
{
    __shared__ alignas(16) __hip_bfloat16 As[2][4][128][8];
    __shared__ alignas(16) __hip_bfloat16 Bs[2][4][128][8];

    const int tid  = threadIdx.x;
    const int w    = tid >> 6;
    const int lane = tid & 63;
    const int g    = lane >> 4;
    const int r    = lane & 15;
    const int wr   = w >> 1, wc = w & 1;

    const int row0 = blockIdx.y * 128;
    const int col0 = blockIdx.x * 128;

    f32x4 acc[4][4];
#pragma unroll
    for (int m = 0; m < 4; ++m)
#pragma unroll
        for (int n = 0; n < 4; ++n) acc[m][n] = (f32x4)0.0f;

    auto stage = [&](int buf, int kt) {
        const __hip_bfloat16* ga = A  + (size_t)(row0 + lane) * KDIM + kt*32 + 8*w;
        const __hip_bfloat16* gb = Bt + (size_t)(col0 + lane) * KDIM + kt*32 + 8*w;
        gl_lds16(ga,            &As[buf][w][0][0]);
        gl_lds16(ga + 64*KDIM,  &As[buf][w][64][0]);
        gl_lds16(gb,            &Bs[buf][w][0][0]);
        gl_lds16(gb + 64*KDIM,  &Bs[buf][w][64][0]);
    };

    stage(0, 0);
    __syncthreads();

    const int NKT = KDIM / 32;
    for (int kt = 0; kt < NKT; ++kt) {
        const int cur = kt & 1;
        if (kt + 1 < NKT) stage(cur ^ 1, kt + 1);

        bf16x8 af[4], bfr[4];
#pragma unroll
        for (int m = 0; m < 4; ++m)
            af[m] = *reinterpret_cast<const bf16x8*>(&As[cur][g][64*wr + 16*m + r][0]);
#pragma unroll
        for (int n = 0; n < 4; ++n)
            bfr[n] = *reinterpret_cast<const bf16x8*>(&Bs[cur][g][64*wc + 16*n + r][0]);

#pragma unroll
        for (int m = 0; m < 4; ++m)
#pragma unroll
            for (int n = 0; n < 4; ++n)
                acc[m][n] = mfma16(af[m], bfr[n], acc[m][n]);

        __syncthreads();
    }

#pragma unroll
    for (int n = 0; n < 4; ++n) {
        const int colg = col0 + 64*wc + 16*n + r;
        const float bv_ = bias[colg];
#pragma unroll
        for (int m = 0; m < 4; ++m) {
            const int rowg0 = row0 + 64*wr + 16*m + 4*g;
#pragma unroll
            for (int j = 0; j < 4; ++j) {
                const int rowg = rowg0 + j;
                const float v = (acc[m][n][j] + bv_) * scale;
                if (EPI == 0) {
                    const int b = rowg >> 11, s = rowg & (SEQL-1);
                    const int h = colg >> 6,  d = colg & (HDIM-1);
                    ((__hip_bfloat16*)out)[(((size_t)(b*NHEAD + h) * SEQL + s) << 6) + d] =
                        __float2bfloat16(v);
                } else if (EPI == 1) {
                    const int b = rowg >> 11, s = rowg & (SEQL-1);
                    const int h = colg >> 6,  d = colg & (HDIM-1);
                    ((__hip_bfloat16*)out)[((size_t)(b*NHEAD + h) * HDIM + d) * SEQL + s] =
                        __float2bfloat16(v);
                } else {
                    ((float*)out)[(size_t)rowg * DOUT + colg] = v;
                }
            }
        }
    }
}

// ---------------- causal flash attention ----------------
// Q,K: [B,H,S,64] bf16 (Q pre-scaled by log2e/8).  Vt: [B,H,64,S] bf16.
// ctx out: [B,S,H*64] bf16 (row-major [8192][1024]).
// 4 waves/block, 32 q-rows/wave (2x 16-row m-tiles), 64-key steps.
// Block pairs q-tile bx with q-tile 15-bx for causal load balance.
__global__ __launch_bounds__(256)
void attn_fwd(const __hip_bfloat16* __restrict__ Q,
              const __hip_bfloat16* __restrict__ K,
              const __hip_bfloat16* __restrict__ Vt,
              __hip_bfloat16* __restrict__ ctx)
{
    __shared__ alignas(16) __hip_bfloat16 Ps[4][2][16][64];

    const int tid  = threadIdx.x;
    const int w    = tid >> 6;
    const int lane = tid & 63;
    const int g    = lane >> 4;
    const int r    = lane & 15;

    const int bh = blockIdx.y;
    const int b  = bh >> 4, h = bh & 15;

    const __hip_bfloat16* Qh = Q  + (size_t)bh * SEQL * HDIM;
    const __hip_bfloat16* Kh = K  + (size_t)bh * SEQL * HDIM;
    const __hip_bfloat16* Vh = Vt + (size_t)bh * HDIM * SEQL;

#pragma unroll 1
    for (int ti = 0; ti < 2; ++ti) {
        const int tile = ti ? (15 - (int)blockIdx.x) : (int)blockIdx.x;
        const int qb = tile * 128 + w * 32;

        bf16x8 qf[2][2];
#pragma unroll
        for (int m = 0; m < 2; ++m)
#pragma unroll
            for (int hh = 0; hh < 2; ++hh)
                qf[m][hh] = *reinterpret_cast<const bf16x8*>(
                    Qh + (size_t)(qb + 16*m + r) * HDIM + 32*hh + 8*g);

        f32x4 o[2][4];
        float mrun[2][4], lrun[2][4];
#pragma unroll
        for (int m = 0; m < 2; ++m) {
#pragma unroll
            for (int n = 0; n < 4; ++n) o[m][n] = (f32x4)0.0f;
#pragma unroll
            for (int j = 0; j < 4; ++j) { mrun[m][j] = -1e30f; lrun[m][j] = 0.0f; }
        }

        const int nst = (qb >> 6) + 1;
#pragma unroll 1
        for (int kt = 0; kt < nst; ++kt) {
            const int key0 = kt * 64;

            bf16x8 kf[4][2];
#pragma unroll
            for (int c = 0; c < 4; ++c)
#pragma unroll
                for (int hh = 0; hh < 2; ++hh)
                    kf[c][hh] = *reinterpret_cast<const bf16x8*>(
                        Kh + (size_t)(key0 + 16*c + r) * HDIM + 32*hh + 8*g);

            f32x4 s[2][4];
#pragma unroll
            for (int m = 0; m < 2; ++m)
#pragma unroll
                for (int c = 0; c < 4; ++c) {
                    f32x4 t = (f32x4)0.0f;
                    t = mfma16(qf[m][0], kf[c][0], t);
                    t = mfma16(qf[m][1], kf[c][1], t);
                    s[m][c] = t;
                }

            if (kt == nst - 1) {   // causal mask only in the boundary step
#pragma unroll
                for (int m = 0; m < 2; ++m)
#pragma unroll
                    for (int c = 0; c < 4; ++c) {
                        const int key = key0 + 16*c + r;
#pragma unroll
                        for (int j = 0; j < 4; ++j)
                            if (key > qb + 16*m + 4*g + j) s[m][c][j] = -1e30f;
                    }
            }

#pragma unroll
            for (int m = 0; m < 2; ++m) {
                // row max over 64 keys: 4 c-tiles in regs + 16-lane shuffle groups
                float tmax[4];
#pragma unroll
                for (int j = 0; j < 4; ++j)
                    tmax[j] = fmaxf(fmaxf(s[m][0][j], s[m][1][j]),
                                    fmaxf(s[m][2][j], s[m][3][j]));
#pragma unroll
                for (int off = 1; off < 16; off <<= 1)
#pragma unroll
                    for (int j = 0; j < 4; ++j)
                        tmax[j] = fmaxf(tmax[j], __shfl_xor(tmax[j], off, 16));

                float fac[4];
#pragma unroll
                for (int j = 0; j < 4; ++j) {
                    const float mnew = fmaxf(mrun[m][j], tmax[j]);
                    fac[j] = exp2f(mrun[m][j] - mnew);   // log2-domain
                    mrun[m][j] = mnew;
                }
#pragma unroll
                for (int c = 0; c < 4; ++c)
#pragma unroll
                    for (int j = 0; j < 4; ++j)
                        s[m][c][j] = exp2f(s[m][c][j] - mrun[m][j]);

                float psum[4];
#pragma unroll
                for (int j = 0; j < 4; ++j)
                    psum[j] = (s[m][0][j] + s[m][1][j]) + (s[m][2][j] + s[m][3][j]);
#pragma unroll
                for (int off = 1; off < 16; off <<= 1)
#pragma unroll
                    for (int j = 0; j < 4; ++j)
                        psum[j] += __shfl_xor(psum[j], off, 16);
#pragma unroll
                for (int j = 0; j < 4; ++j)
                    lrun[m][j] = lrun[m][j] * fac[j] + psum[j];
#pragma unroll
                for (int n = 0; n < 4; ++n)
#pragma unroll
                    for (int j = 0; j < 4; ++j)
                        o[m][n][j] *= fac[j];

                // P (C-layout) -> bf16 -> LDS (XOR-swizzled columns)
#pragma unroll
                for (int c = 0; c < 4; ++c)
#pragma unroll
                    for (int j = 0; j < 4; ++j)
                        Ps[w][m][4*g + j][(16*c + r) ^ (g << 4)] =
                            __float2bfloat16(s[m][c][j]);
            }

            // P A-fragments (swizzled read) + PV
            bf16x8 pf[2][2];
#pragma unroll
            for (int m = 0; m < 2; ++m)
#pragma unroll
                for (int hh = 0; hh < 2; ++hh)
                    pf[m][hh] = *reinterpret_cast<const bf16x8*>(
                        &Ps[w][m][r][(32*hh + 8*g) ^ ((r >> 2) << 4)]);

#pragma unroll
            for (int n = 0; n < 4; ++n) {
                bf16x8 vf0 = *reinterpret_cast<const bf16x8*>(
                    Vh + (size_t)(16*n + r) * SEQL + key0 + 8*g);
                bf16x8 vf1 = *reinterpret_cast<const bf16x8*>(
                    Vh + (size_t)(16*n + r) * SEQL + key0 + 32 + 8*g);
#pragma unroll
                for (int m = 0; m < 2; ++m) {
                    o[m][n] = mfma16(pf[m][0], vf0, o[m][n]);
                    o[m][n] = mfma16(pf[m][1], vf1, o[m][n]);
                }
            }
        }

        float inv[2][4];
#pragma unroll
        for (int m = 0; m < 2; ++m)
#pragma unroll
            for (int j = 0; j < 4; ++j) inv[m][j] = 1.0f / lrun[m][j];
#pragma unroll
        for (int m = 0; m < 2; ++m)
#pragma unroll
            for (int n = 0; n < 4; ++n)
#pragma unroll
                for (int j = 0; j < 4; ++j) {
                    const int srow = qb + 16*m + 4*g + j;
                    const int col  = h*HDIM + 16*n + r;
                    ctx[(size_t)(b*SEQL + srow) * DOUT + col] =
                        __float2bfloat16(o[m][n][j] * inv[m][j]);
                }
    }
}

extern "C" void kernel_launch(void* const* d_in, const int* in_sizes, int n_in,
                              void* d_out, int out_size, void* d_ws, size_t ws_size,
                              hipStream_t stream) {
    const float* x  = (const float*)d_in[0];
    const float* Wq = (const float*)d_in[1];
    const float* bq = (const float*)d_in[2];
    const float* Wk = (const float*)d_in[3];
    const float* bk = (const float*)d_in[4];
    const float* Wv = (const float*)d_in[5];
    const float* bv = (const float*)d_in[6];
    const float* Wo = (const float*)d_in[7];
    const float* bo = (const float*)d_in[8];
    float* out = (float*)d_out;
    (void)in_sizes; (void)n_in; (void)out_size; (void)ws_size;

    char* ws = (char*)d_ws;
    __hip_bfloat16* xb  = (__hip_bfloat16*)ws;                       // 16 MB
    __hip_bfloat16* Wqt = (__hip_bfloat16*)(ws + (16u << 20));       // 4 x 2 MB
    __hip_bfloat16* Wkt = Wqt + (size_t)DOUT * DIN;
    __hip_bfloat16* Wvt = Wkt + (size_t)DOUT * DIN;
    __hip_bfloat16* Wot = Wvt + (size_t)DOUT * DIN;
    __hip_bfloat16* Qb  = (__hip_bfloat16*)(ws + (24u << 20));       // 16 MB
    __hip_bfloat16* Kb  = Qb + (size_t)MTOT * DOUT;                  // 16 MB
    __hip_bfloat16* Vtb = Kb + (size_t)MTOT * DOUT;                  // 16 MB
    __hip_bfloat16* ctx = xb;  // alias: xb dead after the QKV GEMMs

    cvt_bf16<<<2048, 256, 0, stream>>>((const float4*)x, (ushort4*)xb, MTOT * DIN / 4);

    dim3 tb(32, 8), tg(32, 32);
    transpose_cvt<<<tg, tb, 0, stream>>>(Wq, Wqt);
    transpose_cvt<<<tg, tb, 0, stream>>>(Wk, Wkt);
    transpose_cvt<<<tg, tb, 0, stream>>>(Wv, Wvt);
    transpose_cvt<<<tg, tb, 0, stream>>>(Wo, Wot);

    dim3 gg(DOUT / 128, MTOT / 128);  // (8, 64)
    // Q scale: 1/sqrt(64) * log2(e) so softmax runs in exp2 domain
    gemm_mfma<0><<<gg, 256, 0, stream>>>(xb, Wqt, bq, Qb, 0.125f * 1.44269504088896f);
    gemm_mfma<0><<<gg, 256, 0, stream>>>(xb, Wkt, bk, Kb, 1.0f);     // K
    gemm_mfma<1><<<gg, 256, 0, stream>>>(xb, Wvt, bv, Vtb, 1.0f);    // V transposed

    dim3 ag(8, BSZ * NHEAD);  // 8 paired q-tile blocks x 64 (b,h)
    attn_fwd<<<ag, 256, 0, stream>>>(Qb, Kb, Vtb, ctx);

    gemm_mfma<2><<<gg, 256, 0, stream>>>(ctx, Wot, bo, out, 1.0f);   // out proj, f32
}

// Round 3
// 316.055 us; speedup vs baseline: 1.9856x; 1.0529x over previous
//
#include <hip/hip_runtime.h>
#include <hip/hip_bf16.h>
#include <stdint.h>

#define DIN   1024
#define DOUT  1024
#define NHEAD 16
#define HDIM  64
#define SEQL  2048
#define BSZ   4
#define MTOT  (BSZ*SEQL)   // 8192
#define KDIM  1024

typedef __bf16 bf16x8 __attribute__((ext_vector_type(8)));
typedef float  f32x4  __attribute__((ext_vector_type(4)));

__device__ __forceinline__ f32x4 mfma16(bf16x8 a, bf16x8 b, f32x4 c) {
    return __builtin_amdgcn_mfma_f32_16x16x32_bf16(a, b, c, 0, 0, 0);
}

__device__ __forceinline__ void gl_lds16(const void* gsrc, void* ldst) {
    __builtin_amdgcn_global_load_lds(
        (const __attribute__((address_space(1))) uint32_t*)gsrc,
        (__attribute__((address_space(3))) uint32_t*)ldst, 16, 0, 0);
}

__device__ __forceinline__ unsigned short f2bf(float f) {
    union { __hip_bfloat16 h; unsigned short u; } cv;
    cv.h = __float2bfloat16(f);
    return cv.u;
}

// ---------------- fp32 -> bf16 elementwise (vectorized) ----------------
__global__ void cvt_bf16(const float4* __restrict__ in, ushort4* __restrict__ out, int n4) {
    int idx = blockIdx.x * blockDim.x + threadIdx.x;
    int stride = gridDim.x * blockDim.x;
    for (int i = idx; i < n4; i += stride) {
        float4 v = in[i];
        ushort4 o;
        o.x = f2bf(v.x); o.y = f2bf(v.y); o.z = f2bf(v.z); o.w = f2bf(v.w);
        out[i] = o;
    }
}

// ---- transpose + convert 3x W[1024][1024] f32 -> one Wt3[3072][1024] bf16 ----
__global__ void transpose_cvt3(const float* __restrict__ W0, const float* __restrict__ W1,
                               const float* __restrict__ W2, __hip_bfloat16* __restrict__ Wt3) {
    __shared__ __hip_bfloat16 t[32][33];
    const int tx = threadIdx.x, ty = threadIdx.y;   // (32, 8)
    const int bx = blockIdx.x, by = blockIdx.y, z = blockIdx.z;
    const float* W = (z == 0) ? W0 : (z == 1) ? W1 : W2;
    __hip_bfloat16* Wt = Wt3 + (size_t)z * DOUT * DIN;
#pragma unroll
    for (int r = 0; r < 4; ++r)
        t[ty + 8*r][tx] = __float2bfloat16(W[(size_t)(by*32 + ty + 8*r) * DOUT + bx*32 + tx]);
    __syncthreads();
#pragma unroll
    for (int r = 0; r < 4; ++r)
        Wt[(size_t)(bx*32 + ty + 8*r) * DIN + by*32 + tx] = t[tx][ty + 8*r];
}

__global__ void transpose_cvt(const float* __restrict__ W, __hip_bfloat16* __restrict__ Wt) {
    __shared__ __hip_bfloat16 t[32][33];
    const int tx = threadIdx.x, ty = threadIdx.y;
    const int bx = blockIdx.x, by = blockIdx.y;
#pragma unroll
    for (int r = 0; r < 4; ++r)
        t[ty + 8*r][tx] = __float2bfloat16(W[(size_t)(by*32 + ty + 8*r) * DOUT + bx*32 + tx]);
    __syncthreads();
#pragma unroll
    for (int r = 0; r < 4; ++r)
        Wt[(size_t)(bx*32 + ty + 8*r) * DIN + by*32 + tx] = t[tx][ty + 8*r];
}

// ---------------- 128x128-tile MFMA GEMM: C = A[M,K] * Bt[N,K]^T + bias ----------------
// EPI 2: f32 out, row-major [M,N]; bias b0, out o0.
// EPI 3: fused QKV. N=3072: slab0->Q (head-major, *scale), slab1->K (head-major),
//        slab2->V transposed [B,H,64,S]. biases b0,b1,b2; outs o0,o1,o2.
template <int EPI>
__global__ __launch_bounds__(256)
void gemm_mfma(const __hip_bfloat16* __restrict__ A,
               const __hip_bfloat16* __restrict__ Bt,
               const float* __restrict__ b0, const float* __restrict__ b1,
               const float* __restrict__ b2,
               void* __restrict__ o0, void* __restrict__ o1, void* __restrict__ o2,
               float scale)
{
    __shared__ alignas(16) __hip_bfloat16 As[2][4][128][8];
    __shared__ alignas(16) __hip_bfloat16 Bs[2][4][128][8];

    const int tid  = threadIdx.x;
    const int w    = tid >> 6;
    const int lane = tid & 63;
    const int g    = lane >> 4;
    const int r    = lane & 15;
    const int wr   = w >> 1, wc = w & 1;

    const int row0 = blockIdx.y * 128;
    const int col0 = blockIdx.x * 128;

    f32x4 acc[4][4];
#pragma unroll
    for (int m = 0; m < 4; ++m)
#pragma unroll
        for (int n = 0; n < 4; ++n) acc[m][n] = (f32x4)0.0f;

    auto stage = [&](int buf, int kt) {
        const __hip_bfloat16* ga = A  + (size_t)(row0 + lane) * KDIM + kt*32 + 8*w;
        const __hip_bfloat16* gb = Bt + (size_t)(col0 + lane) * KDIM + kt*32 + 8*w;
        gl_lds16(ga,            &As[buf][w][0][0]);
        gl_lds16(ga + 64*KDIM,  &As[buf][w][64][0]);
        gl_lds16(gb,            &Bs[buf][w][0][0]);
        gl_lds16(gb + 64*KDIM,  &Bs[buf][w][64][0]);
    };

    stage(0, 0);
    __syncthreads();

    const int NKT = KDIM / 32;
    for (int kt = 0; kt < NKT; ++kt) {
        const int cur = kt & 1;
        if (kt + 1 < NKT) stage(cur ^ 1, kt + 1);

        bf16x8 af[4], bfr[4];
#pragma unroll
        for (int m = 0; m < 4; ++m)
            af[m] = *reinterpret_cast<const bf16x8*>(&As[cur][g][64*wr + 16*m + r][0]);
#pragma unroll
        for (int n = 0; n < 4; ++n)
            bfr[n] = *reinterpret_cast<const bf16x8*>(&Bs[cur][g][64*wc + 16*n + r][0]);

#pragma unroll
        for (int m = 0; m < 4; ++m)
#pragma unroll
            for (int n = 0; n < 4; ++n)
                acc[m][n] = mfma16(af[m], bfr[n], acc[m][n]);

        __syncthreads();
    }

#pragma unroll
    for (int n = 0; n < 4; ++n) {
        const int colg = col0 + 64*wc + 16*n + r;
        if (EPI == 2) {
            const float bv_ = b0[colg];
#pragma unroll
            for (int m = 0; m < 4; ++m) {
                const int rowg0 = row0 + 64*wr + 16*m + 4*g;
#pragma unroll
                for (int j = 0; j < 4; ++j)
                    ((float*)o0)[(size_t)(rowg0 + j) * DOUT + colg] = acc[m][n][j] + bv_;
            }
        } else {  // EPI == 3
            const int slab = colg >> 10;
            const int c2   = colg & 1023;
            const float* bp = (slab == 0) ? b0 : (slab == 1) ? b1 : b2;
            const float bv_ = bp[c2];
            const int hh = c2 >> 6, dd = c2 & (HDIM-1);
#pragma unroll
            for (int m = 0; m < 4; ++m) {
                const int rowg0 = row0 + 64*wr + 16*m + 4*g;
#pragma unroll
                for (int j = 0; j < 4; ++j) {
                    const int rowg = rowg0 + j;
                    const int bb = rowg >> 11, sq = rowg & (SEQL-1);
                    const float v = acc[m][n][j] + bv_;
                    if (slab == 0)
                        ((__hip_bfloat16*)o0)[(((size_t)(bb*NHEAD + hh) * SEQL + sq) << 6) + dd] =
                            __float2bfloat16(v * scale);
                    else if (slab == 1)
                        ((__hip_bfloat16*)o1)[(((size_t)(bb*NHEAD + hh) * SEQL + sq) << 6) + dd] =
                            __float2bfloat16(v);
                    else
                        ((__hip_bfloat16*)o2)[((size_t)(bb*NHEAD + hh) * HDIM + dd) * SEQL + sq] =
                            __float2bfloat16(v);
                }
            }
        }
    }
}

// ---------------- causal flash attention (swapped-operand layout) ----------------
// Q,K: [B,H,S,64] bf16 (Q pre-scaled by log2e/8).  Vt: [B,H,64,S] bf16.
// ctx out: [B,S,H*64] bf16.
// 4 waves/block; each wave owns 32-row strip pair (sp, 63-sp) for causal balance.
// QK^T computed as mfma(K,Q) -> lane holds S^T[key][qrow]: all 16 scores in a lane
// share one q-row (= qb+16m+r) -> row-reduce = in-reg tree + 2 shuffles; rescale per-lane.
// PV computed as mfma(V^T, P^T) -> O^T, epilogue also per-lane-row.
__global__ __launch_bounds__(256)
void attn_fwd(const __hip_bfloat16* __restrict__ Q,
              const __hip_bfloat16* __restrict__ K,
              const __hip_bfloat16* __restrict__ Vt,
              __hip_bfloat16* __restrict__ ctx)
{
    __shared__ alignas(16) __hip_bfloat16 Ps[4][2][16][64];

    const int tid  = threadIdx.x;
    const int w    = tid >> 6;
    const int lane = tid & 63;
    const int g    = lane >> 4;
    const int r    = lane & 15;
    const int swz  = (r & 7) << 3;   // element-XOR within a 64-elt (128B) row

    const int bh = blockIdx.y;
    const int b  = bh >> 4, h = bh & 15;

    const __hip_bfloat16* Qh = Q  + (size_t)bh * SEQL * HDIM;
    const __hip_bfloat16* Kh = K  + (size_t)bh * SEQL * HDIM;
    const __hip_bfloat16* Vh = Vt + (size_t)bh * HDIM * SEQL;

    const int sp = blockIdx.x * 4 + w;   // 0..31

#pragma unroll 1
    for (int ti = 0; ti < 2; ++ti) {
        const int strip = ti ? (63 - sp) : sp;
        const int qb = strip * 32;

        bf16x8 qf[2][2];
#pragma unroll
        for (int m = 0; m < 2; ++m)
#pragma unroll
            for (int hh = 0; hh < 2; ++hh)
                qf[m][hh] = *reinterpret_cast<const bf16x8*>(
                    Qh + (size_t)(qb + 16*m + r) * HDIM + 32*hh + 8*g);

        f32x4 o[2][4];
        float mrow[2], lrow[2];
#pragma unroll
        for (int m = 0; m < 2; ++m) {
#pragma unroll
            for (int n = 0; n < 4; ++n) o[m][n] = (f32x4)0.0f;
            mrow[m] = -1e30f; lrow[m] = 0.0f;
        }

        const int nst = ((qb + 31) >> 6) + 1;
#pragma unroll 1
        for (int kt = 0; kt < nst; ++kt) {
            const int key0 = kt * 64;

            bf16x8 kf[4][2];
#pragma unroll
            for (int c = 0; c < 4; ++c)
#pragma unroll
                for (int hh = 0; hh < 2; ++hh)
                    kf[c][hh] = *reinterpret_cast<const bf16x8*>(
                        Kh + (size_t)(key0 + 16*c + r) * HDIM + 32*hh + 8*g);

            // S^T[key = key0+16c+4g+j][qrow = qb+16m+r]
            f32x4 s[2][4];
#pragma unroll
            for (int m = 0; m < 2; ++m)
#pragma unroll
                for (int c = 0; c < 4; ++c) {
                    f32x4 t = (f32x4)0.0f;
                    t = mfma16(kf[c][0], qf[m][0], t);
                    t = mfma16(kf[c][1], qf[m][1], t);
                    s[m][c] = t;
                }

            if (kt == nst - 1) {   // causal mask only in the boundary step
#pragma unroll
                for (int m = 0; m < 2; ++m) {
                    const int qrow = qb + 16*m + r;
#pragma unroll
                    for (int c = 0; c < 4; ++c) {
                        const int kb = key0 + 16*c + 4*g;
#pragma unroll
                        for (int j = 0; j < 4; ++j)
                            if (kb + j > qrow) s[m][c][j] = -1e30f;
                    }
                }
            }

#pragma unroll
            for (int m = 0; m < 2; ++m) {
                // row-max: in-reg tree (16 vals, one q-row) + 2 cross-lane hops
                float t0 = fmaxf(fmaxf(s[m][0][0], s[m][0][1]), fmaxf(s[m][0][2], s[m][0][3]));
                float t1 = fmaxf(fmaxf(s[m][1][0], s[m][1][1]), fmaxf(s[m][1][2], s[m][1][3]));
                float t2 = fmaxf(fmaxf(s[m][2][0], s[m][2][1]), fmaxf(s[m][2][2], s[m][2][3]));
                float t3 = fmaxf(fmaxf(s[m][3][0], s[m][3][1]), fmaxf(s[m][3][2], s[m][3][3]));
                float pm = fmaxf(fmaxf(t0, t1), fmaxf(t2, t3));
                pm = fmaxf(pm, __shfl_xor(pm, 16));
                pm = fmaxf(pm, __shfl_xor(pm, 32));

                // defer-max: rescale only when max grew materially (log2 domain)
                if (__any(pm > mrow[m] + 11.0f)) {
                    const float mnew = fmaxf(mrow[m], pm);
                    const float fac  = exp2f(mrow[m] - mnew);
                    mrow[m] = mnew;
                    lrow[m] *= fac;
#pragma unroll
                    for (int n = 0; n < 4; ++n) o[m][n] *= fac;
                }

                float p[4][4];
#pragma unroll
                for (int c = 0; c < 4; ++c)
#pragma unroll
                    for (int j = 0; j < 4; ++j)
                        p[c][j] = exp2f(s[m][c][j] - mrow[m]);

                float u0 = (p[0][0] + p[0][1]) + (p[0][2] + p[0][3]);
                float u1 = (p[1][0] + p[1][1]) + (p[1][2] + p[1][3]);
                float u2 = (p[2][0] + p[2][1]) + (p[2][2] + p[2][3]);
                float u3 = (p[3][0] + p[3][1]) + (p[3][2] + p[3][3]);
                float ps = (u0 + u1) + (u2 + u3);
                ps += __shfl_xor(ps, 16);
                ps += __shfl_xor(ps, 32);
                lrow[m] += ps;

                // pack P row-fragment: 4 bf16 per c -> swizzled ds_write_b64
#pragma unroll
                for (int c = 0; c < 4; ++c) {
                    ushort4 pk4;
                    pk4.x = f2bf(p[c][0]); pk4.y = f2bf(p[c][1]);
                    pk4.z = f2bf(p[c][2]); pk4.w = f2bf(p[c][3]);
                    *reinterpret_cast<ushort4*>(&Ps[w][m][r][(16*c + 4*g) ^ swz]) = pk4;
                }
            }

            // P fragments (swizzled b128 reads) + PV as mfma(V^T, P^T)
            bf16x8 pf[2][2];
#pragma unroll
            for (int m = 0; m < 2; ++m)
#pragma unroll
                for (int hh = 0; hh < 2; ++hh)
                    pf[m][hh] = *reinterpret_cast<const bf16x8*>(
                        &Ps[w][m][r][(32*hh + 8*g) ^ swz]);

#pragma unroll
            for (int n = 0; n < 4; ++n) {
                bf16x8 vf0 = *reinterpret_cast<const bf16x8*>(
                    Vh + (size_t)(16*n + r) * SEQL + key0 + 8*g);
                bf16x8 vf1 = *reinterpret_cast<const bf16x8*>(
                    Vh + (size_t)(16*n + r) * SEQL + key0 + 32 + 8*g);
#pragma unroll
                for (int m = 0; m < 2; ++m) {
                    o[m][n] = mfma16(vf0, pf[m][0], o[m][n]);
                    o[m][n] = mfma16(vf1, pf[m][1], o[m][n]);
                }
            }
        }

        // epilogue: O^T fragment -> ctx row-major; per-lane row, 8B packed stores
#pragma unroll
        for (int m = 0; m < 2; ++m) {
            const float inv = 1.0f / lrow[m];
            const size_t rowbase = (size_t)(b*SEQL + qb + 16*m + r) * DOUT + h*HDIM;
#pragma unroll
            for (int n = 0; n < 4; ++n) {
                ushort4 ov;
                ov.x = f2bf(o[m][n][0] * inv); ov.y = f2bf(o[m][n][1] * inv);
                ov.z = f2bf(o[m][n][2] * inv); ov.w = f2bf(o[m][n][3] * inv);
                *reinterpret_cast<ushort4*>(&ctx[rowbase + 16*n + 4*g]) = ov;
            }
        }
    }
}

extern "C" void kernel_launch(void* const* d_in, const int* in_sizes, int n_in,
                              void* d_out, int out_size, void* d_ws, size_t ws_size,
                              hipStream_t stream) {
    const float* x  = (const float*)d_in[0];
    const float* Wq = (const float*)d_in[1];
    const float* bq = (const float*)d_in[2];
    const float* Wk = (const float*)d_in[3];
    const float* bk = (const float*)d_in[4];
    const float* Wv = (const float*)d_in[5];
    const float* bv = (const float*)d_in[6];
    const float* Wo = (const float*)d_in[7];
    const float* bo = (const float*)d_in[8];
    float* out = (float*)d_out;
    (void)in_sizes; (void)n_in; (void)out_size; (void)ws_size;

    char* ws = (char*)d_ws;
    __hip_bfloat16* xb  = (__hip_bfloat16*)ws;                       // 16 MB
    __hip_bfloat16* Wt3 = (__hip_bfloat16*)(ws + (16u << 20));       // 6 MB (Q,K,V slabs)
    __hip_bfloat16* Wot = (__hip_bfloat16*)(ws + (22u << 20));       // 2 MB
    __hip_bfloat16* Qb  = (__hip_bfloat16*)(ws + (24u << 20));       // 16 MB
    __hip_bfloat16* Kb  = Qb + (size_t)MTOT * DOUT;                  // 16 MB
    __hip_bfloat16* Vtb = Kb + (size_t)MTOT * DOUT;                  // 16 MB
    __hip_bfloat16* ctx = xb;  // alias: xb dead after the QKV GEMM

    cvt_bf16<<<2048, 256, 0, stream>>>((const float4*)x, (ushort4*)xb, MTOT * DIN / 4);

    dim3 tb(32, 8);
    transpose_cvt3<<<dim3(32, 32, 3), tb, 0, stream>>>(Wq, Wk, Wv, Wt3);
    transpose_cvt <<<dim3(32, 32),    tb, 0, stream>>>(Wo, Wot);

    // fused QKV GEMM: N = 3072. Q scale folds 1/sqrt(64) * log2(e) for exp2 softmax.
    dim3 gq(3*DOUT / 128, MTOT / 128);  // (24, 64)
    gemm_mfma<3><<<gq, 256, 0, stream>>>(xb, Wt3, bq, bk, bv, Qb, Kb, Vtb,
                                         0.125f * 1.44269504088896f);

    dim3 ag(8, BSZ * NHEAD);  // 32 strip-pairs per bh / 4 waves = 8 blocks x 64 (b,h)
    attn_fwd<<<ag, 256, 0, stream>>>(Qb, Kb, Vtb, ctx);

    dim3 gg(DOUT / 128, MTOT / 128);  // (8, 64)
    gemm_mfma<2><<<gg, 256, 0, stream>>>(ctx, Wot, bo, nullptr, nullptr,
                                         out, nullptr, nullptr, 1.0f);
}